// Round 2
// baseline (1116.691 us; speedup 1.0000x reference)
//
#include <hip/hip_runtime.h>
#include <stdint.h>

#define NNODES 16384
#define DDIM   256
#define NLEV   16
#define KDEG   16

typedef _Float16 half8  __attribute__((ext_vector_type(8)));
typedef _Float16 half4_t __attribute__((ext_vector_type(4)));
typedef float    f32x4  __attribute__((ext_vector_type(4)));

__device__ __forceinline__ void async_copy16(const void* g, void* l) {
  __builtin_amdgcn_global_load_lds(
      (const __attribute__((address_space(1))) unsigned int*)(uintptr_t)g,
      (__attribute__((address_space(3))) unsigned int*)(uintptr_t)l,
      16, 0, 0);
}

// Transpose+cast both weight matrices: Wt[n][k] = (f16) W[k][n]
__global__ __launch_bounds__(256) void convert_w_kernel(
    const float* __restrict__ W1, const float* __restrict__ W2,
    _Float16* __restrict__ W1t, _Float16* __restrict__ W2t) {
  int t = blockIdx.x * 256 + threadIdx.x;   // 65536 threads
  int k = t >> 8, n = t & 255;
  W1t[n * 256 + k] = (_Float16)W1[t];
  W2t[n * 256 + k] = (_Float16)W2[t];
}

// out[0] = x[0]; y16 = f16(x[0])
__global__ __launch_bounds__(256) void init_kernel(
    const float* __restrict__ x0, float* __restrict__ out0,
    _Float16* __restrict__ y16) {
  size_t t = (size_t)blockIdx.x * 256 + threadIdx.x;  // 1048576 threads * 4 floats
  f32x4 v = *(const f32x4*)(x0 + t * 4);
  *(f32x4*)(out0 + t * 4) = v;
  half4_t h;
  h[0] = (_Float16)v[0]; h[1] = (_Float16)v[1];
  h[2] = (_Float16)v[2]; h[3] = (_Float16)v[3];
  *(half4_t*)(y16 + t * 4) = h;
}

// C[M=16384 x 256] = act(A[16384x256] @ W[256x256] + bias)
// A: f16 row-major. Wt: f16 [col][k] (pre-transposed). BM=64, BN=128, BK=32.
// 4 waves (2x2), each wave 32x64 (2x4 frags of 16x16x32 f16 MFMA).
// LDS layout [k_hi][row][k_lo8] f16 -> conflict-free ds_read_b128, linear
// global_load_lds staging (16B per lane).
template <bool FINAL>
__global__ __launch_bounds__(256) void gemm_kernel(
    const _Float16* __restrict__ A, const _Float16* __restrict__ Wt,
    const float* __restrict__ bias, const float* __restrict__ xres,
    _Float16* __restrict__ o16, float* __restrict__ o32) {
  __shared__ __align__(16) unsigned char smem[12288];
  unsigned char* As = smem;          // 4096 B: [khi(4)][row(64)][klo(8)] f16
  unsigned char* Bs = smem + 4096;   // 8192 B: [khi(4)][col(128)][klo(8)] f16

  const int tid  = threadIdx.x;
  const int lane = tid & 63;
  const int w    = tid >> 6;
  const int wr   = w >> 1, wc = w & 1;
  const int tm   = blockIdx.x >> 1, tn = blockIdx.x & 1;

  f32x4 acc[2][4];
#pragma unroll
  for (int i = 0; i < 2; ++i)
#pragma unroll
    for (int j = 0; j < 4; ++j) acc[i][j] = (f32x4)(0.0f);

  // A staging: one 16B op/thread. o = tid*16 -> khi = o>>10, row = (o>>4)&63
  const int a_khi = tid >> 6;
  const int a_row = tid & 63;
  const _Float16* a_src = A + (size_t)(tm * 64 + a_row) * 256 + a_khi * 8;
  // B staging: two 16B ops/thread. o = tid*16 + i*4096
  const int b_o0   = tid * 16;
  const int b_khi0 = b_o0 >> 11;
  const int b_col0 = (b_o0 >> 4) & 127;
  const int b_o1   = tid * 16 + 4096;
  const int b_khi1 = b_o1 >> 11;
  const int b_col1 = (b_o1 >> 4) & 127;
  const _Float16* b_src0 = Wt + (size_t)(tn * 128 + b_col0) * 256 + b_khi0 * 8;
  const _Float16* b_src1 = Wt + (size_t)(tn * 128 + b_col1) * 256 + b_khi1 * 8;

  const int kh  = lane >> 4;
  const int r15 = lane & 15;

  for (int kt = 0; kt < 8; ++kt) {
    const int k0 = kt * 32;
    async_copy16(a_src + k0, As + tid * 16);
    async_copy16(b_src0 + k0, Bs + b_o0);
    async_copy16(b_src1 + k0, Bs + b_o1);
    __syncthreads();  // drains vmcnt -> staged data visible

    half8 af[2], bf[4];
#pragma unroll
    for (int mf = 0; mf < 2; ++mf)
      af[mf] = *(const half8*)(As + kh * 1024 + (wr * 32 + mf * 16 + r15) * 16);
#pragma unroll
    for (int nf = 0; nf < 4; ++nf)
      bf[nf] = *(const half8*)(Bs + kh * 2048 + (wc * 64 + nf * 16 + r15) * 16);
#pragma unroll
    for (int mf = 0; mf < 2; ++mf)
#pragma unroll
      for (int nf = 0; nf < 4; ++nf)
        acc[mf][nf] = __builtin_amdgcn_mfma_f32_16x16x32_f16(
            af[mf], bf[nf], acc[mf][nf], 0, 0, 0);
    __syncthreads();  // all waves done reading before next stage
  }

  // epilogue: C frag layout col = lane&15, row = (lane>>4)*4 + j
#pragma unroll
  for (int mf = 0; mf < 2; ++mf) {
    const int rbase = tm * 64 + wr * 32 + mf * 16 + (lane >> 4) * 4;
#pragma unroll
    for (int nf = 0; nf < 4; ++nf) {
      const int col = tn * 128 + wc * 64 + nf * 16 + (lane & 15);
      const float bv = bias[col];
#pragma unroll
      for (int j = 0; j < 4; ++j) {
        const size_t off = (size_t)(rbase + j) * 256 + col;
        float v = acc[mf][nf][j] + bv;
        v = fmaxf(v, 0.0f);
        if (FINAL) {
          float y = v + xres[off];
          o32[off] = y;
          o16[off] = (_Float16)y;
        } else {
          o16[off] = (_Float16)v;
        }
      }
    }
  }
}

// z[i] = f16( mean_k msg[idx[i][k]] ), f32 accumulate.
// Half-wave (32 lanes) per node: 16B (8 f16) per lane -> 512B coalesced per row.
__global__ __launch_bounds__(256) void gather_kernel(
    const _Float16* __restrict__ msg, const int* __restrict__ idx,
    _Float16* __restrict__ z) {
  const int tid  = threadIdx.x;
  const int node = blockIdx.x * 8 + (tid >> 5);
  const int c8   = (tid & 31) * 8;
  const int* ip  = idx + (size_t)node * KDEG;
  float acc[8] = {0, 0, 0, 0, 0, 0, 0, 0};
#pragma unroll
  for (int k = 0; k < KDEG; ++k) {
    const int r = ip[k];
    half8 v = *(const half8*)(msg + (size_t)r * 256 + c8);
#pragma unroll
    for (int j = 0; j < 8; ++j) acc[j] += (float)v[j];
  }
  half8 o;
#pragma unroll
  for (int j = 0; j < 8; ++j) o[j] = (_Float16)(acc[j] * 0.0625f);
  *(half8*)(z + (size_t)node * 256 + c8) = o;
}

extern "C" void kernel_launch(void* const* d_in, const int* in_sizes, int n_in,
                              void* d_out, int out_size, void* d_ws, size_t ws_size,
                              hipStream_t stream) {
  const float* x   = (const float*)d_in[0];
  const int*   idx = (const int*)d_in[1];
  const float* W1  = (const float*)d_in[2];
  const float* b1  = (const float*)d_in[3];
  const float* W2  = (const float*)d_in[4];
  const float* b2  = (const float*)d_in[5];
  float* out = (float*)d_out;

  char* ws = (char*)d_ws;
  _Float16* W1t = (_Float16*)(ws);
  _Float16* W2t = (_Float16*)(ws + 131072);
  _Float16* y16 = (_Float16*)(ws + 262144);               // 8 MB
  _Float16* msg = (_Float16*)(ws + 262144 + 8388608);     // 8 MB
  _Float16* z16 = (_Float16*)(ws + 262144 + 16777216);    // 8 MB
  const size_t ND = (size_t)NNODES * DDIM;

  convert_w_kernel<<<dim3(256), dim3(256), 0, stream>>>(W1, W2, W1t, W2t);
  init_kernel<<<dim3(4096), dim3(256), 0, stream>>>(x, out, y16);

  for (int l = 1; l < NLEV; ++l) {
    gemm_kernel<false><<<dim3(512), dim3(256), 0, stream>>>(
        y16, W1t, b1, nullptr, msg, nullptr);
    gather_kernel<<<dim3(2048), dim3(256), 0, stream>>>(
        msg, idx + (size_t)(l - 1) * NNODES * KDEG, z16);
    gemm_kernel<true><<<dim3(512), dim3(256), 0, stream>>>(
        z16, W2t, b2, x + (size_t)l * ND, y16, out + (size_t)l * ND);
  }
}

// Round 3
// 1029.408 us; speedup vs baseline: 1.0848x; 1.0848x over previous
//
#include <hip/hip_runtime.h>
#include <stdint.h>

#define NN 16384
#define DD 256
#define LV 16
#define KD 16

typedef _Float16 half8 __attribute__((ext_vector_type(8)));
typedef _Float16 half4v __attribute__((ext_vector_type(4)));
typedef float f32x4 __attribute__((ext_vector_type(4)));
typedef int i32x4 __attribute__((ext_vector_type(4)));

// Transpose+cast weights: Wt[n][k] = (f16) W[k][n]
__global__ __launch_bounds__(256) void convert_w_kernel(
    const float* __restrict__ W1, const float* __restrict__ W2,
    _Float16* __restrict__ W1t, _Float16* __restrict__ W2t) {
  int t = blockIdx.x * 256 + threadIdx.x;  // 65536
  int k = t >> 8, n = t & 255;
  W1t[n * 256 + k] = (_Float16)W1[t];
  W2t[n * 256 + k] = (_Float16)W2[t];
}

// out[0] = x[0]; y16 = f16(x[0])
__global__ __launch_bounds__(256) void init_kernel(
    const float* __restrict__ x0, float* __restrict__ out0,
    _Float16* __restrict__ y16) {
  size_t t = (size_t)blockIdx.x * 256 + threadIdx.x;
  f32x4 v = *(const f32x4*)(x0 + t * 4);
  *(f32x4*)(out0 + t * 4) = v;
  half4v h;
  h[0] = (_Float16)v[0]; h[1] = (_Float16)v[1];
  h[2] = (_Float16)v[2]; h[3] = (_Float16)v[3];
  *(half4v*)(y16 + t * 4) = h;
}

// K1: msg = relu(y @ W1 + b1).  LDS-free, barrier-free: each wave owns a
// 32x64 tile; A/B MFMA fragments are read straight from global (L1/L2-hot:
// per instruction the wave touches 16 x 64B fully-used segments).
__global__ __launch_bounds__(256, 2) void msg_gemm_kernel(
    const _Float16* __restrict__ A, const _Float16* __restrict__ Wt,
    const float* __restrict__ bias, _Float16* __restrict__ o16) {
  const int bid = blockIdx.x;                   // 512
  const int s   = (bid & 7) * 64 + (bid >> 3);  // XCD-chunked (512%8==0)
  const int tm  = s;                            // rows tm*32
  const int tn  = threadIdx.x >> 6;             // wave -> 64-col slice
  const int lane = threadIdx.x & 63;
  const int r15 = lane & 15, kh = lane >> 4;    // kh in [0,4): 8-k chunk

  f32x4 acc[2][4];
#pragma unroll
  for (int i = 0; i < 2; ++i)
#pragma unroll
    for (int j = 0; j < 4; ++j) acc[i][j] = (f32x4)(0.f);

  const _Float16* a0 = A  + (size_t)(tm * 32 + r15) * 256 + kh * 8;
  const _Float16* b0 = Wt + (size_t)(tn * 64 + r15) * 256 + kh * 8;
#pragma unroll
  for (int kt = 0; kt < 8; ++kt) {
    half8 af[2], bf[4];
#pragma unroll
    for (int mf = 0; mf < 2; ++mf)
      af[mf] = *(const half8*)(a0 + mf * 4096 + kt * 32);  // +16 rows
#pragma unroll
    for (int nf = 0; nf < 4; ++nf)
      bf[nf] = *(const half8*)(b0 + nf * 4096 + kt * 32);  // +16 cols
#pragma unroll
    for (int mf = 0; mf < 2; ++mf)
#pragma unroll
      for (int nf = 0; nf < 4; ++nf)
        acc[mf][nf] = __builtin_amdgcn_mfma_f32_16x16x32_f16(
            af[mf], bf[nf], acc[mf][nf], 0, 0, 0);
  }
#pragma unroll
  for (int mf = 0; mf < 2; ++mf) {
    const int rbase = tm * 32 + mf * 16 + kh * 4;
#pragma unroll
    for (int nf = 0; nf < 4; ++nf) {
      const int col = tn * 64 + nf * 16 + r15;
      const float bv = bias[col];
#pragma unroll
      for (int j = 0; j < 4; ++j) {
        float v = fmaxf(acc[mf][nf][j] + bv, 0.f);
        o16[(size_t)(rbase + j) * 256 + col] = (_Float16)v;
      }
    }
  }
}

// K2: fused gather-mean + GEMM2 + bias/relu/residual + dual store.
// Block = 32 nodes x all 256 cols, 512 threads (8 waves).
// Phase 1: thread (r=t>>4, cc=t&15) gathers 16 parents x 16 cols, f32 acc,
//          writes f16 A-tile to LDS [kt8][khi4][row32][klo8] ^ (kt<<4) swizzle.
// Phase 2 (after ONE barrier): wave w owns cols w*32; B frags direct from
//          L2-hot W2t; epilogue adds residual, stores f32 out + f16 y.
__global__ __launch_bounds__(512, 2) void gather_gemm_kernel(
    const _Float16* __restrict__ msg, const int* __restrict__ idxl,
    const _Float16* __restrict__ Wt2, const float* __restrict__ bias,
    const float* __restrict__ xres, _Float16* __restrict__ y16,
    float* __restrict__ o32) {
  __shared__ __align__(16) unsigned char As[16384];
  const int bid = blockIdx.x;                   // 512
  const int s   = (bid & 7) * 64 + (bid >> 3);  // XCD-chunked
  const int tid = threadIdx.x;

  {  // ---- gather phase ----
    const int r = tid >> 4, cc = tid & 15;
    const int node = s * 32 + r;
    const int* ip = idxl + (size_t)node * KD;
    i32x4 q0 = *(const i32x4*)(ip);
    i32x4 q1 = *(const i32x4*)(ip + 4);
    i32x4 q2 = *(const i32x4*)(ip + 8);
    i32x4 q3 = *(const i32x4*)(ip + 12);
    const int pidx[16] = {q0[0], q0[1], q0[2], q0[3], q1[0], q1[1], q1[2], q1[3],
                          q2[0], q2[1], q2[2], q2[3], q3[0], q3[1], q3[2], q3[3]};
    float acc[16];
#pragma unroll
    for (int j = 0; j < 16; ++j) acc[j] = 0.f;
#pragma unroll
    for (int p = 0; p < 16; ++p) {
      const _Float16* src = msg + (size_t)pidx[p] * 256 + cc * 16;
      half8 v0 = *(const half8*)(src);
      half8 v1 = *(const half8*)(src + 8);
#pragma unroll
      for (int j = 0; j < 8; ++j) {
        acc[j] += (float)v0[j];
        acc[8 + j] += (float)v1[j];
      }
    }
    half8 h0, h1;
#pragma unroll
    for (int j = 0; j < 8; ++j) {
      h0[j] = (_Float16)(acc[j] * 0.0625f);
      h1[j] = (_Float16)(acc[8 + j] * 0.0625f);
    }
    const int kt = cc >> 1;
    const int kb = (cc & 1) * 2;
    const unsigned o0 = (unsigned)((kt * 2048 + kb * 512 + r * 16) ^ (kt << 4));
    const unsigned o1 = (unsigned)((kt * 2048 + (kb + 1) * 512 + r * 16) ^ (kt << 4));
    *(half8*)(As + o0) = h0;
    *(half8*)(As + o1) = h1;
  }
  __syncthreads();

  // ---- GEMM phase ----
  const int lane = tid & 63, w = tid >> 6;      // w = 64-thread wave id, cols w*32
  const int r15 = lane & 15, kh = lane >> 4;
  f32x4 acc2[2][2];
#pragma unroll
  for (int i = 0; i < 2; ++i)
#pragma unroll
    for (int j = 0; j < 2; ++j) acc2[i][j] = (f32x4)(0.f);

  const _Float16* b0 = Wt2 + (size_t)(w * 32 + r15) * 256 + kh * 8;
#pragma unroll
  for (int kt = 0; kt < 8; ++kt) {
    half8 af[2], bf[2];
#pragma unroll
    for (int mf = 0; mf < 2; ++mf)
      af[mf] = *(const half8*)(As +
          ((kt * 2048 + kh * 512 + (mf * 16 + r15) * 16) ^ (kt << 4)));
#pragma unroll
    for (int nf = 0; nf < 2; ++nf)
      bf[nf] = *(const half8*)(b0 + nf * 4096 + kt * 32);
#pragma unroll
    for (int mf = 0; mf < 2; ++mf)
#pragma unroll
      for (int nf = 0; nf < 2; ++nf)
        acc2[mf][nf] = __builtin_amdgcn_mfma_f32_16x16x32_f16(
            af[mf], bf[nf], acc2[mf][nf], 0, 0, 0);
  }
#pragma unroll
  for (int mf = 0; mf < 2; ++mf) {
    const int rbase = s * 32 + mf * 16 + kh * 4;
#pragma unroll
    for (int nf = 0; nf < 2; ++nf) {
      const int col = w * 32 + nf * 16 + r15;
      const float bv = bias[col];
#pragma unroll
      for (int j = 0; j < 4; ++j) {
        const size_t off = (size_t)(rbase + j) * 256 + col;
        float v = fmaxf(acc2[mf][nf][j] + bv, 0.f) + xres[off];
        o32[off] = v;
        y16[off] = (_Float16)v;
      }
    }
  }
}

extern "C" void kernel_launch(void* const* d_in, const int* in_sizes, int n_in,
                              void* d_out, int out_size, void* d_ws, size_t ws_size,
                              hipStream_t stream) {
  const float* x   = (const float*)d_in[0];
  const int*   idx = (const int*)d_in[1];
  const float* W1  = (const float*)d_in[2];
  const float* b1  = (const float*)d_in[3];
  const float* W2  = (const float*)d_in[4];
  const float* b2  = (const float*)d_in[5];
  float* out = (float*)d_out;

  char* ws = (char*)d_ws;
  _Float16* W1t = (_Float16*)(ws);
  _Float16* W2t = (_Float16*)(ws + 131072);
  _Float16* y16 = (_Float16*)(ws + 262144);             // 8 MB
  _Float16* msg = (_Float16*)(ws + 262144 + 8388608);   // 8 MB
  const size_t ND = (size_t)NN * DD;

  convert_w_kernel<<<dim3(256), dim3(256), 0, stream>>>(W1, W2, W1t, W2t);
  init_kernel<<<dim3(4096), dim3(256), 0, stream>>>(x, out, y16);

  for (int l = 1; l < LV; ++l) {
    msg_gemm_kernel<<<dim3(512), dim3(256), 0, stream>>>(y16, W1t, b1, msg);
    gather_gemm_kernel<<<dim3(512), dim3(512), 0, stream>>>(
        msg, idx + (size_t)(l - 1) * NN * KD, W2t, b2,
        x + (size_t)l * ND, y16, out + (size_t)l * ND);
  }
}